// Round 20
// baseline (687.150 us; speedup 1.0000x reference)
//
#include <hip/hip_runtime.h>
#include <stdint.h>

typedef short bf16x8 __attribute__((ext_vector_type(8)));
typedef float f32x4 __attribute__((ext_vector_type(4)));

#define NROWS 50000
#define BATCH 32
#define SEQ 256
#define DIN 768
#define DMODEL 1024
#define NTOPK 5
#define DOTS_RG 782       // row groups: ceil(50000 / 64)
#define CHUNKF 64         // k-floats per chunk
#define NCHUNK_HALF 8     // 512 / 64 per K-half

__device__ inline unsigned short f2bf(float f) {
  union { float f; unsigned u; } x; x.f = f;
  unsigned u = x.u;
  unsigned r = u + 0x7fffu + ((u >> 16) & 1u);
  return (unsigned short)(r >> 16);
}
__device__ inline float bf2f(unsigned short h) {
  union { unsigned u; float f; } x; x.u = ((unsigned)h) << 16; return x.f;
}
__device__ inline ushort4 cvt_hi4(float4 f) {
  ushort4 h; h.x = f2bf(f.x); h.y = f2bf(f.y); h.z = f2bf(f.z); h.w = f2bf(f.w); return h;
}
__device__ inline ushort4 cvt_lo4(float4 f, ushort4 h) {
  ushort4 l;
  l.x = f2bf(f.x - bf2f(h.x)); l.y = f2bf(f.y - bf2f(h.y));
  l.z = f2bf(f.z - bf2f(h.z)); l.w = f2bf(f.w - bf2f(h.w));
  return l;
}

__device__ __forceinline__ void gl_lds16(const void* g, void* l) {
  __builtin_amdgcn_global_load_lds(
      (const __attribute__((address_space(1))) unsigned int*)g,
      (__attribute__((address_space(3))) unsigned int*)l, 16, 0, 0);
}

// ---------------- fused: hidden fp32->bf16 convert + partial mean ----------------
__global__ void k_hidden_prep(const float* __restrict__ hidden, unsigned short* __restrict__ hid_bf,
                              float* __restrict__ hpart) {
  int b = blockIdx.x >> 3, tc = blockIdx.x & 7;
  int i = threadIdx.x;
  const float* p = hidden + ((size_t)b * SEQ + tc * 32) * DIN + i;
  unsigned short* o = hid_bf + ((size_t)b * SEQ + tc * 32) * DIN + i;
  float s = 0.f;
  #pragma unroll 4
  for (int t = 0; t < 32; ++t) {
    float v = p[t * DIN];
    s += v;
    o[t * DIN] = f2bf(v);
  }
  hpart[((size_t)tc * 32 + b) * DIN + i] = s;
}

__global__ void k_mean_reduce(const float* __restrict__ hpart, float* __restrict__ hm) {
  int b = blockIdx.x;          // 32
  int i = threadIdx.x;         // 768
  float s = 0.f;
  #pragma unroll
  for (int tc = 0; tc < 8; ++tc) s += hpart[((size_t)tc * 32 + b) * DIN + i];
  hm[b * DIN + i] = s * (1.0f / SEQ);
}

// three tensors in one launch
__global__ void k_f32_to_bf16_3(const float* __restrict__ i0, unsigned short* __restrict__ o0, int n0,
                                const float* __restrict__ i1, unsigned short* __restrict__ o1, int n1,
                                const float* __restrict__ i2, unsigned short* __restrict__ o2, int n2) {
  int base = (blockIdx.x * blockDim.x + threadIdx.x) * 4;
  int stride = gridDim.x * blockDim.x * 4;
  for (int i = base; i < n0; i += stride) {
    float4 f = *(const float4*)(i0 + i);
    ushort4 o; o.x = f2bf(f.x); o.y = f2bf(f.y); o.z = f2bf(f.z); o.w = f2bf(f.w);
    *(ushort4*)(o0 + i) = o;
  }
  for (int i = base; i < n1; i += stride) {
    float4 f = *(const float4*)(i1 + i);
    ushort4 o; o.x = f2bf(f.x); o.y = f2bf(f.y); o.z = f2bf(f.z); o.w = f2bf(f.w);
    *(ushort4*)(o1 + i) = o;
  }
  for (int i = base; i < n2; i += stride) {
    float4 f = *(const float4*)(i2 + i);
    ushort4 o; o.x = f2bf(f.x); o.y = f2bf(f.y); o.z = f2bf(f.z); o.w = f2bf(f.w);
    *(ushort4*)(o2 + i) = o;
  }
}

// ---------------- split queries into bf16 hi/lo ----------------
__global__ void k_split_q(const float* __restrict__ v, unsigned short* __restrict__ qhi,
                          unsigned short* __restrict__ qlo) {
  int b = blockIdx.x;                // 32
  int e0 = threadIdx.x * 4;          // 256 threads x 4
  float4 f = *(const float4*)(v + (size_t)b * DMODEL + e0);
  ushort4 h = cvt_hi4(f);
  ushort4 l = cvt_lo4(f, h);
  *(ushort4*)(qhi + (size_t)b * DMODEL + e0) = h;
  *(ushort4*)(qlo + (size_t)b * DMODEL + e0) = l;
}

// ---------------- small fp32 GEMM: C[M,N] = A[M,K] @ W[N,K]^T + beta*bias ----------------
__global__ void k_sgemm_wt(const float* __restrict__ A, const float* __restrict__ W,
                           const float* __restrict__ bias, float* __restrict__ C,
                           int M, int N, int K, float beta) {
  __shared__ float A_l[32][65];
  __shared__ float W_l[64][65];
  int tid = threadIdx.x;            // 256
  int tx = tid & 63, ty = tid >> 6; // ty = wave
  int n0 = blockIdx.x * 64, m0 = blockIdx.y * 32;
  float acc[8] = {0.f,0.f,0.f,0.f,0.f,0.f,0.f,0.f};
  for (int k0 = 0; k0 < K; k0 += 64) {
    #pragma unroll
    for (int i = 0; i < 8; ++i) {
      int idx = tid + 256 * i; int r = idx >> 6, c = idx & 63;
      A_l[r][c] = A[(size_t)(m0 + r) * K + k0 + c];
    }
    #pragma unroll
    for (int i = 0; i < 16; ++i) {
      int idx = tid + 256 * i; int r = idx >> 6, c = idx & 63;
      W_l[r][c] = W[(size_t)(n0 + r) * K + k0 + c];
    }
    __syncthreads();
    for (int kk = 0; kk < 64; ++kk) {
      float wv = W_l[tx][kk];
      #pragma unroll
      for (int r = 0; r < 8; ++r) acc[r] += A_l[ty * 8 + r][kk] * wv;
    }
    __syncthreads();
  }
  float bv = bias[n0 + tx] * beta;
  #pragma unroll
  for (int r = 0; r < 8; ++r) C[(size_t)(m0 + ty * 8 + r) * N + n0 + tx] = acc[r] + bv;
}

// ---------------- bf16 MFMA GEMM: C[M,N](bf16) = A[M,K]bf16 @ W[N,K]bf16^T + bias ------
// bias2 non-null: cols >= N0 use bias2[col-N0] (merged K|V projection).
__global__ __launch_bounds__(256) void k_bf16_gemm(const unsigned short* __restrict__ A,
    const unsigned short* __restrict__ W, const float* __restrict__ bias,
    const float* __restrict__ bias2, int N0,
    unsigned short* __restrict__ C, int M, int N, int K) {
  __shared__ unsigned short As[128][32];
  __shared__ unsigned short Ws[128][32];
  int tid = threadIdx.x;
  int wave = tid >> 6, lane = tid & 63;
  int wr = wave >> 1, wc = wave & 1;
  int bm = blockIdx.y * 128, bn = blockIdx.x * 128;
  int srow = lane >> 2;        // 0..15
  int scol = (lane & 3) * 8;   // element offset within 32-elem k-slice
  f32x4 acc[4][4] = {};
  for (int k0 = 0; k0 < K; k0 += 32) {
    #pragma unroll
    for (int j = 0; j < 2; ++j) {
      int r0 = wave * 32 + j * 16;
      gl_lds16(A + (size_t)(bm + r0 + srow) * K + k0 + scol, &As[r0][0]);
      gl_lds16(W + (size_t)(bn + r0 + srow) * K + k0 + scol, &Ws[r0][0]);
    }
    __syncthreads();
    bf16x8 af[4], bfr[4];
    #pragma unroll
    for (int mi = 0; mi < 4; ++mi)
      af[mi] = *(const bf16x8*)(&As[wr * 64 + mi * 16 + (lane & 15)][(lane >> 4) * 8]);
    #pragma unroll
    for (int ni = 0; ni < 4; ++ni)
      bfr[ni] = *(const bf16x8*)(&Ws[wc * 64 + ni * 16 + (lane & 15)][(lane >> 4) * 8]);
    #pragma unroll
    for (int mi = 0; mi < 4; ++mi)
      #pragma unroll
      for (int ni = 0; ni < 4; ++ni)
        acc[mi][ni] = __builtin_amdgcn_mfma_f32_16x16x32_bf16(af[mi], bfr[ni], acc[mi][ni], 0, 0, 0);
    __syncthreads();
  }
  #pragma unroll
  for (int ni = 0; ni < 4; ++ni) {
    int col = bn + wc * 64 + ni * 16 + (lane & 15);
    float bv = (bias2 != nullptr && col >= N0) ? bias2[col - N0] : bias[col];
    #pragma unroll
    for (int mi = 0; mi < 4; ++mi) {
      #pragma unroll
      for (int j = 0; j < 4; ++j) {
        int row = bm + wr * 64 + mi * 16 + (lane >> 4) * 4 + j;
        C[(size_t)row * N + col] = f2bf(acc[mi][ni][j] + bv);
      }
    }
  }
}

// ---------------- retrieval v11: 8-wave K-split dots with 2-deep table prefetch ----------
// As v10, but chunk loop unrolled x2 with static reg sets A/B: LOAD_A(c+2) issues at
// chunk c, so each table load's latency is covered by two full chunks of compute.
__global__ __launch_bounds__(512, 8) void k_dots(const float* __restrict__ table,
    const unsigned short* __restrict__ qhi, const unsigned short* __restrict__ qlo,
    float* __restrict__ normp, float* __restrict__ dotsg, int pass1) {
  __shared__ unsigned short As_hi[2][64 * 64];   // 16 KB
  __shared__ unsigned short As_lo[2][64 * 64];   // 16 KB
  __shared__ float npart[64][8];
  float* dot_lds = (float*)&As_hi[0][0];         // [32][68] fp32, aliased after main loop

  int tid = threadIdx.x;
  int wave = tid >> 6, lane = tid & 63;
  int rg = blockIdx.x >> 1, half = blockIdx.x & 1;
  int rbase = rg * 64;
  int kbase = half * 512;

  // staging: thread -> (row r = tid>>3, slot g = tid&7 covering 8 floats)
  int r = tid >> 3;
  int g = tid & 7;
  int grow = rbase + r; if (grow >= NROWS) grow = NROWS - 1;
  const float* gsrc = table + (size_t)grow * DMODEL + kbase + g * 8;
  int wslot = (g ^ (r & 7)) * 8;
  int wbase = r * 64;

  // compute: wave (w&3) -> rows, (w>>2) -> batch half
  int abase = ((wave & 3) * 16 + (lane & 15)) * 64;
  int al7 = lane & 7;
  int b0 = (wave >> 2) * 16;
  const unsigned short* qh = qhi + (size_t)(b0 + (lane & 15)) * DMODEL + (lane >> 4) * 8 + kbase;
  const unsigned short* ql = qlo + (size_t)(b0 + (lane & 15)) * DMODEL + (lane >> 4) * 8 + kbase;

  float accn = 0.f;
  f32x4 acc = {};
  float4 fA0, fA1, fB0, fB1;

  auto LOAD_A = [&](int k0) {
    fA0 = *(const float4*)(gsrc + k0);
    fA1 = *(const float4*)(gsrc + k0 + 4);
  };
  auto LOAD_B = [&](int k0) {
    fB0 = *(const float4*)(gsrc + k0);
    fB1 = *(const float4*)(gsrc + k0 + 4);
  };
  auto WRITE = [&](int buf, float4 f0, float4 f1) {
    ushort4 h0 = cvt_hi4(f0), h1 = cvt_hi4(f1);
    ushort4 l0 = cvt_lo4(f0, h0), l1 = cvt_lo4(f1, h1);
    accn += f0.x*f0.x + f0.y*f0.y + f0.z*f0.z + f0.w*f0.w
          + f1.x*f1.x + f1.y*f1.y + f1.z*f1.z + f1.w*f1.w;
    *(ushort4*)&As_hi[buf][wbase + wslot]     = h0;
    *(ushort4*)&As_hi[buf][wbase + wslot + 4] = h1;
    *(ushort4*)&As_lo[buf][wbase + wslot]     = l0;
    *(ushort4*)&As_lo[buf][wbase + wslot + 4] = l1;
  };
  auto COMPUTE = [&](int buf, int k0) {
    bf16x8 bh[2], bl[2];
    #pragma unroll
    for (int kk = 0; kk < 2; ++kk) {
      int qoff = k0 + kk * 32;
      bh[kk] = *(const bf16x8*)(qh + qoff);
      bl[kk] = *(const bf16x8*)(ql + qoff);
    }
    __syncthreads();   // chunk staged by all waves; also orders buffer reuse
    #pragma unroll
    for (int kk = 0; kk < 2; ++kk) {
      int s = ((kk * 4 + (lane >> 4)) ^ al7) * 8;
      bf16x8 ah = *(const bf16x8*)&As_hi[buf][abase + s];
      bf16x8 al = *(const bf16x8*)&As_lo[buf][abase + s];
      acc = __builtin_amdgcn_mfma_f32_16x16x32_bf16(ah, bh[kk], acc, 0, 0, 0);
      acc = __builtin_amdgcn_mfma_f32_16x16x32_bf16(ah, bl[kk], acc, 0, 0, 0);
      acc = __builtin_amdgcn_mfma_f32_16x16x32_bf16(al, bh[kk], acc, 0, 0, 0);
    }
  };

  LOAD_A(0);
  LOAD_B(CHUNKF);
  #pragma unroll
  for (int cp = 0; cp < NCHUNK_HALF / 2; ++cp) {
    int c0 = cp * 2;
    // even chunk (reg set A -> buf 0)
    WRITE(0, fA0, fA1);
    if (c0 + 2 < NCHUNK_HALF) LOAD_A((c0 + 2) * CHUNKF);
    COMPUTE(0, c0 * CHUNKF);
    // odd chunk (reg set B -> buf 1)
    WRITE(1, fB0, fB1);
    if (c0 + 3 < NCHUNK_HALF) LOAD_B((c0 + 3) * CHUNKF);
    COMPUTE(1, (c0 + 1) * CHUNKF);
  }

  npart[r][g] = accn;
  __syncthreads();   // all MFMA LDS reads done; npart visible
  if (pass1 && tid < 64) {
    int rw = rbase + tid;
    if (rw < NROWS) {
      float n2 = 0.f;
      #pragma unroll
      for (int j = 0; j < 8; ++j) n2 += npart[tid][j];
      normp[(size_t)half * NROWS + rw] = n2;
    }
  }
  // scatter raw dots into LDS [32][68]
  #pragma unroll
  for (int j = 0; j < 4; ++j) {
    int row = (wave & 3) * 16 + (lane >> 4) * 4 + j;
    dot_lds[(b0 + (lane & 15)) * 68 + row] = acc[j];
  }
  __syncthreads();
  // coalesced store: dotsg[((rg*2+half)*32 + b)*64 + row], 512 threads x 4 floats
  {
    int b = tid >> 4, r0 = (tid & 15) * 4;
    float4 v0 = *(const float4*)&dot_lds[b * 68 + r0];
    *(float4*)(dotsg + ((size_t)blockIdx.x * 32 + b) * 64 + r0) = v0;
  }
}

// ---------------- combine K-halves + normalize + per-rg top-5 ----------------
__global__ void k_comb5(const float* __restrict__ dotsg, const float* __restrict__ normp,
                        float* __restrict__ norm2f, float* __restrict__ candv,
                        int* __restrict__ candi, int pass1, float eps) {
  __shared__ float sc[32 * 68];
  __shared__ float iv_lds[64];
  int rg = blockIdx.x;
  int tid = threadIdx.x;  // 256
  if (tid < 64) {
    int rw = rg * 64 + tid;
    int rc = rw < NROWS ? rw : NROWS - 1;
    float n2;
    if (pass1) {
      n2 = normp[rc] + normp[NROWS + rc];
      if (rw < NROWS) norm2f[rw] = n2;
    } else {
      n2 = norm2f[rc];
    }
    iv_lds[tid] = 1.0f / fmaxf(sqrtf(n2), eps);
  }
  __syncthreads();
  {
    int b = tid >> 3, r0 = (tid & 7) * 8;
    const float* p0 = dotsg + ((size_t)(rg * 2 + 0) * 32 + b) * 64 + r0;
    const float* p1 = dotsg + ((size_t)(rg * 2 + 1) * 32 + b) * 64 + r0;
    #pragma unroll
    for (int i = 0; i < 8; ++i)
      sc[b * 68 + r0 + i] = (p0[i] + p1[i]) * iv_lds[r0 + i];
  }
  __syncthreads();
  if (tid < 32) {
    float tv[5]; int ti[5];
    #pragma unroll
    for (int j = 0; j < 5; ++j) { tv[j] = -3.4e38f; ti[j] = 0x7fffffff; }
    int rbase = rg * 64;
    for (int rr = 0; rr < 64; ++rr) {
      int rw = rbase + rr;
      if (rw >= NROWS) break;
      float v = sc[tid * 68 + rr];
      if (v > tv[4] || (v == tv[4] && rw < ti[4])) {
        tv[4] = v; ti[4] = rw;
        #pragma unroll
        for (int j = 4; j > 0; --j) {
          bool sw = (tv[j] > tv[j-1]) || (tv[j] == tv[j-1] && ti[j] < ti[j-1]);
          if (sw) {
            float fv = tv[j]; tv[j] = tv[j-1]; tv[j-1] = fv;
            int ivx = ti[j]; ti[j] = ti[j-1]; ti[j-1] = ivx;
          }
        }
      }
    }
    #pragma unroll
    for (int j = 0; j < 5; ++j) {
      candv[((size_t)rg * 32 + tid) * 5 + j] = tv[j];
      candi[((size_t)rg * 32 + tid) * 5 + j] = ti[j];
    }
  }
}

// ---------------- merge per-rg candidates -> global top-K per batch ----------------
__global__ void k_merge(const float* __restrict__ candv, const int* __restrict__ candi,
                        int* __restrict__ out_idx, int K, int nblk) {
  int b = blockIdx.x;
  int tid = threadIdx.x; // 256
  float tv[5]; int ti[5];
  #pragma unroll
  for (int j = 0; j < 5; ++j) { tv[j] = -3.4e38f; ti[j] = 0x7fffffff; }
  for (int blk = tid; blk < nblk; blk += 256) {
    #pragma unroll
    for (int j = 0; j < 5; ++j) {
      float v = candv[((size_t)blk * 32 + b) * 5 + j];
      int idx = candi[((size_t)blk * 32 + b) * 5 + j];
      if (v > tv[4] || (v == tv[4] && idx < ti[4])) {
        tv[4] = v; ti[4] = idx;
        #pragma unroll
        for (int jj = 4; jj > 0; --jj) {
          bool sw = (tv[jj] > tv[jj-1]) || (tv[jj] == tv[jj-1] && ti[jj] < ti[jj-1]);
          if (sw) {
            float fv = tv[jj]; tv[jj] = tv[jj-1]; tv[jj-1] = fv;
            int ivx = ti[jj]; ti[jj] = ti[jj-1]; ti[jj-1] = ivx;
          }
        }
      }
    }
  }
  __shared__ float lv[256 * 5];
  __shared__ int   li[256 * 5];
  #pragma unroll
  for (int j = 0; j < 5; ++j) { lv[tid * 5 + j] = tv[j]; li[tid * 5 + j] = ti[j]; }
  __syncthreads();
  for (int off = 128; off >= 1; off >>= 1) {
    if (tid < off) {
      float av[5], bv[5]; int ai[5], bi[5];
      #pragma unroll
      for (int j = 0; j < 5; ++j) {
        av[j] = lv[tid * 5 + j]; ai[j] = li[tid * 5 + j];
        bv[j] = lv[(tid + off) * 5 + j]; bi[j] = li[(tid + off) * 5 + j];
      }
      int pa = 0, pb = 0;
      float mv[5]; int mi[5];
      #pragma unroll
      for (int j = 0; j < 5; ++j) {
        bool ta = (av[pa] > bv[pb]) || (av[pa] == bv[pb] && ai[pa] < bi[pb]);
        if (ta) { mv[j] = av[pa]; mi[j] = ai[pa]; ++pa; }
        else    { mv[j] = bv[pb]; mi[j] = bi[pb]; ++pb; }
      }
      #pragma unroll
      for (int j = 0; j < 5; ++j) { lv[tid * 5 + j] = mv[j]; li[tid * 5 + j] = mi[j]; }
    }
    __syncthreads();
  }
  if (tid == 0) {
    for (int j = 0; j < K; ++j) out_idx[b * K + j] = li[j];
  }
}

// ---------------- gathers ----------------
__global__ void k_gather_sel(const float* __restrict__ table, const int* __restrict__ best,
                             float* __restrict__ sel) {
  int b = blockIdx.x, e = threadIdx.x; // 1024
  int idx = best[b];
  sel[b * DMODEL + e] = table[(size_t)idx * DMODEL + e];
}

__global__ void k_gather_targets(const float* __restrict__ table, const int* __restrict__ idx5,
                                 float* __restrict__ tg) {
  int bt = blockIdx.x, e = threadIdx.x; // 1024
  int idx = idx5[bt];
  tg[(size_t)bt * DMODEL + e] = table[(size_t)idx * DMODEL + e];
}

// ---------------- attention over merged kv buffer [b*SEQ][2048]: K cols 0..1023, V cols 1024..2047 ----
__global__ __launch_bounds__(256) void k_attention(const float* __restrict__ q,
    const unsigned short* __restrict__ kv, float* __restrict__ obuf) {
  int bt = blockIdx.x;
  int b = bt / NTOPK;
  int tid = threadIdx.x; // 256
  __shared__ float q_l[DMODEL];
  __shared__ float sc[4][SEQ];
  #pragma unroll
  for (int j = 0; j < 4; ++j) q_l[tid + 256 * j] = q[(size_t)bt * DMODEL + tid + 256 * j];
  __syncthreads();
  { // scores: thread = key position s
    int s = tid;
    const unsigned short* krow = kv + ((size_t)(b * SEQ + s)) * 2048;
    #pragma unroll
    for (int h = 0; h < 4; ++h) {
      float d = 0.f;
      for (int dd = 0; dd < 256; dd += 8) {
        uint4 pk = *(const uint4*)(krow + h * 256 + dd);
        const unsigned short* ph = (const unsigned short*)&pk;
        #pragma unroll
        for (int j2 = 0; j2 < 8; ++j2) d += bf2f(ph[j2]) * q_l[h * 256 + dd + j2];
      }
      sc[h][s] = d * 0.0625f; // 1/sqrt(256)
    }
  }
  __syncthreads();
  { // softmax: wave w handles head h=w
    int h = tid >> 6, lane = tid & 63;
    float vals[4];
    float mx = -3.4e38f;
    #pragma unroll
    for (int j = 0; j < 4; ++j) { vals[j] = sc[h][lane + 64 * j]; mx = fmaxf(mx, vals[j]); }
    #pragma unroll
    for (int o = 1; o < 64; o <<= 1) mx = fmaxf(mx, __shfl_xor(mx, o));
    float sum = 0.f;
    #pragma unroll
    for (int j = 0; j < 4; ++j) { vals[j] = expf(vals[j] - mx); sum += vals[j]; }
    #pragma unroll
    for (int o = 1; o < 64; o <<= 1) sum += __shfl_xor(sum, o);
    float rz = 1.0f / sum;
    #pragma unroll
    for (int j = 0; j < 4; ++j) sc[h][lane + 64 * j] = vals[j] * rz;
  }
  __syncthreads();
  { // PV: thread owns 4 contiguous output dims
    int h = tid >> 6;
    int e0 = tid * 4;
    float a0 = 0.f, a1 = 0.f, a2 = 0.f, a3 = 0.f;
    const unsigned short* vbase = kv + (size_t)(b * SEQ) * 2048 + 1024 + e0;
    for (int s = 0; s < SEQ; ++s) {
      float w = sc[h][s];
      ushort4 v4 = *(const ushort4*)(vbase + (size_t)s * 2048);
      a0 += w * bf2f(v4.x); a1 += w * bf2f(v4.y); a2 += w * bf2f(v4.z); a3 += w * bf2f(v4.w);
    }
    float* op = obuf + (size_t)bt * DMODEL + e0;
    op[0] = a0; op[1] = a1; op[2] = a2; op[3] = a3;
  }
}

// ---------------- sum over the 5 queries ----------------
__global__ void k_osum(const float* __restrict__ obuf, float* __restrict__ osum) {
  int g = blockIdx.x * blockDim.x + threadIdx.x; // 32768
  if (g >= BATCH * DMODEL) return;
  int b = g >> 10, e = g & 1023;
  float s = 0.f;
  #pragma unroll
  for (int t = 0; t < NTOPK; ++t) s += obuf[(size_t)(b * NTOPK + t) * DMODEL + e];
  osum[g] = s;
}

extern "C" void kernel_launch(void* const* d_in, const int* in_sizes, int n_in,
                              void* d_out, int out_size, void* d_ws, size_t ws_size,
                              hipStream_t stream) {
  const float* hidden = (const float*)d_in[0];
  const float* table  = (const float*)d_in[1];
  const float* fc1_w  = (const float*)d_in[2];
  const float* fc1_b  = (const float*)d_in[3];
  const float* q_w    = (const float*)d_in[4];
  const float* q_b    = (const float*)d_in[5];
  const float* k_w    = (const float*)d_in[6];
  const float* k_b    = (const float*)d_in[7];
  const float* v_w    = (const float*)d_in[8];
  const float* v_b    = (const float*)d_in[9];
  const float* out_w  = (const float*)d_in[10];
  const float* out_b  = (const float*)d_in[11];
  float* out = (float*)d_out;

  char* ws = (char*)d_ws;
  size_t off = 0;
  auto alloc = [&](size_t bytes) -> void* {
    void* p = ws + off;
    off += (bytes + 255) & ~(size_t)255;
    return p;
  };
  unsigned short* hid_bf  = (unsigned short*)alloc((size_t)BATCH * SEQ * DIN * 2);
  unsigned short* fc1w_bf = (unsigned short*)alloc((size_t)DMODEL * DIN * 2);
  unsigned short* kvw_bf  = (unsigned short*)alloc((size_t)2 * DMODEL * DMODEL * 2);
  unsigned short* x_bf    = (unsigned short*)alloc((size_t)BATCH * SEQ * DMODEL * 2);
  unsigned short* kv_bf   = (unsigned short*)alloc((size_t)BATCH * SEQ * 2 * DMODEL * 2);
  unsigned short* qhi     = (unsigned short*)alloc((size_t)BATCH * DMODEL * 2);
  unsigned short* qlo     = (unsigned short*)alloc((size_t)BATCH * DMODEL * 2);
  float* hpart   = (float*)alloc((size_t)8 * BATCH * DIN * 4);
  float* hm      = (float*)alloc((size_t)BATCH * DIN * 4);
  float* m       = (float*)alloc((size_t)BATCH * DMODEL * 4);
  float* sel     = (float*)alloc((size_t)BATCH * DMODEL * 4);
  float* normp   = (float*)alloc((size_t)2 * NROWS * 4);
  float* norm2f  = (float*)alloc((size_t)NROWS * 4);
  float* dotsg   = (float*)alloc((size_t)DOTS_RG * 2 * 32 * 64 * 4);
  float* candv   = (float*)alloc((size_t)DOTS_RG * 32 * 5 * 4);
  int*   candi   = (int*)alloc((size_t)DOTS_RG * 32 * 5 * 4);
  int*   best    = (int*)alloc(BATCH * 4);
  int*   idx5    = (int*)alloc(BATCH * NTOPK * 4);
  float* targets = (float*)alloc((size_t)BATCH * NTOPK * DMODEL * 4);
  float* qbuf    = (float*)alloc((size_t)BATCH * NTOPK * DMODEL * 4);
  float* obuf    = (float*)alloc((size_t)BATCH * NTOPK * DMODEL * 4);
  float* osum    = (float*)alloc((size_t)BATCH * DMODEL * 4);
  (void)ws_size; (void)in_sizes; (void)n_in; (void)out_size;

  // fused hidden convert + mean partials; weight converts (k_w|v_w -> adjacent halves of kvw_bf)
  k_hidden_prep<<<256, 768, 0, stream>>>(hidden, hid_bf, hpart);
  k_f32_to_bf16_3<<<1024, 256, 0, stream>>>(fc1_w, fc1w_bf, DMODEL * DIN,
                                            k_w, kvw_bf, DMODEL * DMODEL,
                                            v_w, kvw_bf + (size_t)DMODEL * DMODEL, DMODEL * DMODEL);
  k_mean_reduce<<<32, 768, 0, stream>>>(hpart, hm);
  k_sgemm_wt<<<dim3(16, 1), 256, 0, stream>>>(hm, fc1_w, fc1_b, m, 32, DMODEL, DIN, 1.0f);

  // fc1: x (bf16)
  k_bf16_gemm<<<dim3(8, 64), 256, 0, stream>>>(hid_bf, fc1w_bf, fc1_b, nullptr, DMODEL,
                                               x_bf, BATCH * SEQ, DMODEL, DIN);

  // retrieval pass 1: cos argmax (8-wave K-split split-bf16 MFMA dots, 2-deep prefetch)
  k_split_q<<<32, 256, 0, stream>>>(m, qhi, qlo);
  k_dots<<<DOTS_RG * 2, 512, 0, stream>>>(table, qhi, qlo, normp, dotsg, 1);
  k_comb5<<<DOTS_RG, 256, 0, stream>>>(dotsg, normp, norm2f, candv, candi, 1, 1e-6f);
  k_merge<<<32, 256, 0, stream>>>(candv, candi, best, 1, DOTS_RG);
  k_gather_sel<<<32, 1024, 0, stream>>>(table, best, sel);

  // retrieval pass 2: top-5 by dot(sel, t_i)/||t_i|| (ranking-equivalent to ref d2)
  k_split_q<<<32, 256, 0, stream>>>(sel, qhi, qlo);
  k_dots<<<DOTS_RG * 2, 512, 0, stream>>>(table, qhi, qlo, normp, dotsg, 0);
  k_comb5<<<DOTS_RG, 256, 0, stream>>>(dotsg, normp, norm2f, candv, candi, 0, 1e-12f);
  k_merge<<<32, 256, 0, stream>>>(candv, candi, idx5, NTOPK, DOTS_RG);
  k_gather_targets<<<160, 1024, 0, stream>>>(table, idx5, targets);

  // q projection (fp32, small M)
  k_sgemm_wt<<<dim3(16, 5), 256, 0, stream>>>(targets, q_w, q_b, qbuf, BATCH * NTOPK, DMODEL, DMODEL, 1.0f);

  // merged K|V projection: kv = x @ [k_w|v_w]^T + [k_b|v_b]  (one N=2048 GEMM)
  k_bf16_gemm<<<dim3(16, 64), 256, 0, stream>>>(x_bf, kvw_bf, k_b, v_b, DMODEL,
                                                kv_bf, BATCH * SEQ, 2 * DMODEL, DMODEL);

  // attention + sum over queries + output projection
  k_attention<<<160, 256, 0, stream>>>(qbuf, kv_bf, obuf);
  k_osum<<<128, 256, 0, stream>>>(obuf, osum);
  k_sgemm_wt<<<dim3(16, 1), 256, 0, stream>>>(osum, out_w, out_b, out, 32, DMODEL, DMODEL, 5.0f);
}

// Round 21
// 565.155 us; speedup vs baseline: 1.2159x; 1.2159x over previous
//
#include <hip/hip_runtime.h>
#include <stdint.h>

typedef short bf16x8 __attribute__((ext_vector_type(8)));
typedef float f32x4 __attribute__((ext_vector_type(4)));

#define NROWS 50000
#define BATCH 32
#define SEQ 256
#define DIN 768
#define DMODEL 1024
#define NTOPK 5
#define DOTS_RG 782       // row groups: ceil(50000 / 64)
#define CHUNKF 64         // k-floats per chunk
#define NCHUNK_HALF 8     // 512 / 64 per K-half

__device__ inline unsigned short f2bf(float f) {
  union { float f; unsigned u; } x; x.f = f;
  unsigned u = x.u;
  unsigned r = u + 0x7fffu + ((u >> 16) & 1u);
  return (unsigned short)(r >> 16);
}
__device__ inline float bf2f(unsigned short h) {
  union { unsigned u; float f; } x; x.u = ((unsigned)h) << 16; return x.f;
}
__device__ inline ushort4 cvt_hi4(float4 f) {
  ushort4 h; h.x = f2bf(f.x); h.y = f2bf(f.y); h.z = f2bf(f.z); h.w = f2bf(f.w); return h;
}
__device__ inline ushort4 cvt_lo4(float4 f, ushort4 h) {
  ushort4 l;
  l.x = f2bf(f.x - bf2f(h.x)); l.y = f2bf(f.y - bf2f(h.y));
  l.z = f2bf(f.z - bf2f(h.z)); l.w = f2bf(f.w - bf2f(h.w));
  return l;
}

__device__ __forceinline__ void gl_lds16(const void* g, void* l) {
  __builtin_amdgcn_global_load_lds(
      (const __attribute__((address_space(1))) unsigned int*)g,
      (__attribute__((address_space(3))) unsigned int*)l, 16, 0, 0);
}

// ---------------- fused: hidden fp32->bf16 convert + partial mean ----------------
__global__ void k_hidden_prep(const float* __restrict__ hidden, unsigned short* __restrict__ hid_bf,
                              float* __restrict__ hpart) {
  int b = blockIdx.x >> 3, tc = blockIdx.x & 7;
  int i = threadIdx.x;
  const float* p = hidden + ((size_t)b * SEQ + tc * 32) * DIN + i;
  unsigned short* o = hid_bf + ((size_t)b * SEQ + tc * 32) * DIN + i;
  float s = 0.f;
  #pragma unroll 4
  for (int t = 0; t < 32; ++t) {
    float v = p[t * DIN];
    s += v;
    o[t * DIN] = f2bf(v);
  }
  hpart[((size_t)tc * 32 + b) * DIN + i] = s;
}

__global__ void k_mean_reduce(const float* __restrict__ hpart, float* __restrict__ hm) {
  int b = blockIdx.x;          // 32
  int i = threadIdx.x;         // 768
  float s = 0.f;
  #pragma unroll
  for (int tc = 0; tc < 8; ++tc) s += hpart[((size_t)tc * 32 + b) * DIN + i];
  hm[b * DIN + i] = s * (1.0f / SEQ);
}

// three tensors in one launch
__global__ void k_f32_to_bf16_3(const float* __restrict__ i0, unsigned short* __restrict__ o0, int n0,
                                const float* __restrict__ i1, unsigned short* __restrict__ o1, int n1,
                                const float* __restrict__ i2, unsigned short* __restrict__ o2, int n2) {
  int base = (blockIdx.x * blockDim.x + threadIdx.x) * 4;
  int stride = gridDim.x * blockDim.x * 4;
  for (int i = base; i < n0; i += stride) {
    float4 f = *(const float4*)(i0 + i);
    ushort4 o; o.x = f2bf(f.x); o.y = f2bf(f.y); o.z = f2bf(f.z); o.w = f2bf(f.w);
    *(ushort4*)(o0 + i) = o;
  }
  for (int i = base; i < n1; i += stride) {
    float4 f = *(const float4*)(i1 + i);
    ushort4 o; o.x = f2bf(f.x); o.y = f2bf(f.y); o.z = f2bf(f.z); o.w = f2bf(f.w);
    *(ushort4*)(o1 + i) = o;
  }
  for (int i = base; i < n2; i += stride) {
    float4 f = *(const float4*)(i2 + i);
    ushort4 o; o.x = f2bf(f.x); o.y = f2bf(f.y); o.z = f2bf(f.z); o.w = f2bf(f.w);
    *(ushort4*)(o2 + i) = o;
  }
}

// ---------------- split queries into bf16 hi/lo ----------------
__global__ void k_split_q(const float* __restrict__ v, unsigned short* __restrict__ qhi,
                          unsigned short* __restrict__ qlo) {
  int b = blockIdx.x;                // 32
  int e0 = threadIdx.x * 4;          // 256 threads x 4
  float4 f = *(const float4*)(v + (size_t)b * DMODEL + e0);
  ushort4 h = cvt_hi4(f);
  ushort4 l = cvt_lo4(f, h);
  *(ushort4*)(qhi + (size_t)b * DMODEL + e0) = h;
  *(ushort4*)(qlo + (size_t)b * DMODEL + e0) = l;
}

// ---------------- small fp32 GEMM: C[M,N] = A[M,K] @ W[N,K]^T + beta*bias ----------------
__global__ void k_sgemm_wt(const float* __restrict__ A, const float* __restrict__ W,
                           const float* __restrict__ bias, float* __restrict__ C,
                           int M, int N, int K, float beta) {
  __shared__ float A_l[32][65];
  __shared__ float W_l[64][65];
  int tid = threadIdx.x;            // 256
  int tx = tid & 63, ty = tid >> 6; // ty = wave
  int n0 = blockIdx.x * 64, m0 = blockIdx.y * 32;
  float acc[8] = {0.f,0.f,0.f,0.f,0.f,0.f,0.f,0.f};
  for (int k0 = 0; k0 < K; k0 += 64) {
    #pragma unroll
    for (int i = 0; i < 8; ++i) {
      int idx = tid + 256 * i; int r = idx >> 6, c = idx & 63;
      A_l[r][c] = A[(size_t)(m0 + r) * K + k0 + c];
    }
    #pragma unroll
    for (int i = 0; i < 16; ++i) {
      int idx = tid + 256 * i; int r = idx >> 6, c = idx & 63;
      W_l[r][c] = W[(size_t)(n0 + r) * K + k0 + c];
    }
    __syncthreads();
    for (int kk = 0; kk < 64; ++kk) {
      float wv = W_l[tx][kk];
      #pragma unroll
      for (int r = 0; r < 8; ++r) acc[r] += A_l[ty * 8 + r][kk] * wv;
    }
    __syncthreads();
  }
  float bv = bias[n0 + tx] * beta;
  #pragma unroll
  for (int r = 0; r < 8; ++r) C[(size_t)(m0 + ty * 8 + r) * N + n0 + tx] = acc[r] + bv;
}

// ---------------- bf16 MFMA GEMM: C[M,N](bf16) = A[M,K]bf16 @ W[N,K]bf16^T + bias ------
// bias2 non-null: cols >= N0 use bias2[col-N0] (merged K|V projection).
__global__ __launch_bounds__(256) void k_bf16_gemm(const unsigned short* __restrict__ A,
    const unsigned short* __restrict__ W, const float* __restrict__ bias,
    const float* __restrict__ bias2, int N0,
    unsigned short* __restrict__ C, int M, int N, int K) {
  __shared__ unsigned short As[128][32];
  __shared__ unsigned short Ws[128][32];
  int tid = threadIdx.x;
  int wave = tid >> 6, lane = tid & 63;
  int wr = wave >> 1, wc = wave & 1;
  int bm = blockIdx.y * 128, bn = blockIdx.x * 128;
  int srow = lane >> 2;        // 0..15
  int scol = (lane & 3) * 8;   // element offset within 32-elem k-slice
  f32x4 acc[4][4] = {};
  for (int k0 = 0; k0 < K; k0 += 32) {
    #pragma unroll
    for (int j = 0; j < 2; ++j) {
      int r0 = wave * 32 + j * 16;
      gl_lds16(A + (size_t)(bm + r0 + srow) * K + k0 + scol, &As[r0][0]);
      gl_lds16(W + (size_t)(bn + r0 + srow) * K + k0 + scol, &Ws[r0][0]);
    }
    __syncthreads();
    bf16x8 af[4], bfr[4];
    #pragma unroll
    for (int mi = 0; mi < 4; ++mi)
      af[mi] = *(const bf16x8*)(&As[wr * 64 + mi * 16 + (lane & 15)][(lane >> 4) * 8]);
    #pragma unroll
    for (int ni = 0; ni < 4; ++ni)
      bfr[ni] = *(const bf16x8*)(&Ws[wc * 64 + ni * 16 + (lane & 15)][(lane >> 4) * 8]);
    #pragma unroll
    for (int mi = 0; mi < 4; ++mi)
      #pragma unroll
      for (int ni = 0; ni < 4; ++ni)
        acc[mi][ni] = __builtin_amdgcn_mfma_f32_16x16x32_bf16(af[mi], bfr[ni], acc[mi][ni], 0, 0, 0);
    __syncthreads();
  }
  #pragma unroll
  for (int ni = 0; ni < 4; ++ni) {
    int col = bn + wc * 64 + ni * 16 + (lane & 15);
    float bv = (bias2 != nullptr && col >= N0) ? bias2[col - N0] : bias[col];
    #pragma unroll
    for (int mi = 0; mi < 4; ++mi) {
      #pragma unroll
      for (int j = 0; j < 4; ++j) {
        int row = bm + wr * 64 + mi * 16 + (lane >> 4) * 4 + j;
        C[(size_t)row * N + col] = f2bf(acc[mi][ni][j] + bv);
      }
    }
  }
}

// ---------------- retrieval v10: 8-wave K-split split-bf16 MFMA partial dots ----------------
__global__ __launch_bounds__(512, 8) void k_dots(const float* __restrict__ table,
    const unsigned short* __restrict__ qhi, const unsigned short* __restrict__ qlo,
    float* __restrict__ normp, float* __restrict__ dotsg, int pass1) {
  __shared__ unsigned short As_hi[2][64 * 64];   // 16 KB
  __shared__ unsigned short As_lo[2][64 * 64];   // 16 KB
  __shared__ float npart[64][8];
  float* dot_lds = (float*)&As_hi[0][0];         // [32][68] fp32, aliased after main loop

  int tid = threadIdx.x;
  int wave = tid >> 6, lane = tid & 63;
  int rg = blockIdx.x >> 1, half = blockIdx.x & 1;
  int rbase = rg * 64;
  int kbase = half * 512;

  // staging: thread -> (row r = tid>>3, slot g = tid&7 covering 8 floats)
  int r = tid >> 3;
  int g = tid & 7;
  int grow = rbase + r; if (grow >= NROWS) grow = NROWS - 1;
  const float* gsrc = table + (size_t)grow * DMODEL + kbase + g * 8;
  int wslot = (g ^ (r & 7)) * 8;
  int wbase = r * 64;

  // compute: wave (w&3) -> rows, (w>>2) -> batch half
  int abase = ((wave & 3) * 16 + (lane & 15)) * 64;
  int al7 = lane & 7;
  int b0 = (wave >> 2) * 16;
  const unsigned short* qh = qhi + (size_t)(b0 + (lane & 15)) * DMODEL + (lane >> 4) * 8 + kbase;
  const unsigned short* ql = qlo + (size_t)(b0 + (lane & 15)) * DMODEL + (lane >> 4) * 8 + kbase;

  float accn = 0.f;
  f32x4 acc = {};
  float4 f0, f1;

  auto LOAD = [&](int k0) {
    f0 = *(const float4*)(gsrc + k0);
    f1 = *(const float4*)(gsrc + k0 + 4);
  };
  auto WRITE = [&](int buf) {
    ushort4 h0 = cvt_hi4(f0), h1 = cvt_hi4(f1);
    ushort4 l0 = cvt_lo4(f0, h0), l1 = cvt_lo4(f1, h1);
    accn += f0.x*f0.x + f0.y*f0.y + f0.z*f0.z + f0.w*f0.w
          + f1.x*f1.x + f1.y*f1.y + f1.z*f1.z + f1.w*f1.w;
    *(ushort4*)&As_hi[buf][wbase + wslot]     = h0;
    *(ushort4*)&As_hi[buf][wbase + wslot + 4] = h1;
    *(ushort4*)&As_lo[buf][wbase + wslot]     = l0;
    *(ushort4*)&As_lo[buf][wbase + wslot + 4] = l1;
  };

  LOAD(0);
  for (int ch = 0; ch < NCHUNK_HALF; ++ch) {
    int buf = ch & 1;
    int k0 = ch * CHUNKF;
    // preload q fragments for both k-steps (regs; latency overlaps WRITE/barrier)
    bf16x8 bh[2], bl[2];
    #pragma unroll
    for (int kk = 0; kk < 2; ++kk) {
      int qoff = k0 + kk * 32;
      bh[kk] = *(const bf16x8*)(qh + qoff);
      bl[kk] = *(const bf16x8*)(ql + qoff);
    }
    WRITE(buf);
    if (ch + 1 < NCHUNK_HALF) LOAD(k0 + CHUNKF);
    __syncthreads();   // chunk staged by all waves; also orders buffer reuse
    #pragma unroll
    for (int kk = 0; kk < 2; ++kk) {
      int s = ((kk * 4 + (lane >> 4)) ^ al7) * 8;
      bf16x8 ah = *(const bf16x8*)&As_hi[buf][abase + s];
      bf16x8 al = *(const bf16x8*)&As_lo[buf][abase + s];
      acc = __builtin_amdgcn_mfma_f32_16x16x32_bf16(ah, bh[kk], acc, 0, 0, 0);
      acc = __builtin_amdgcn_mfma_f32_16x16x32_bf16(ah, bl[kk], acc, 0, 0, 0);
      acc = __builtin_amdgcn_mfma_f32_16x16x32_bf16(al, bh[kk], acc, 0, 0, 0);
    }
  }

  npart[r][g] = accn;
  __syncthreads();   // all MFMA LDS reads done; npart visible
  if (pass1 && tid < 64) {
    int rw = rbase + tid;
    if (rw < NROWS) {
      float n2 = 0.f;
      #pragma unroll
      for (int j = 0; j < 8; ++j) n2 += npart[tid][j];
      normp[(size_t)half * NROWS + rw] = n2;
    }
  }
  // scatter raw dots into LDS [32][68]
  #pragma unroll
  for (int j = 0; j < 4; ++j) {
    int row = (wave & 3) * 16 + (lane >> 4) * 4 + j;
    dot_lds[(b0 + (lane & 15)) * 68 + row] = acc[j];
  }
  __syncthreads();
  // coalesced store: dotsg[((rg*2+half)*32 + b)*64 + row], 512 threads x 4 floats
  {
    int b = tid >> 4, r0 = (tid & 15) * 4;
    float4 v0 = *(const float4*)&dot_lds[b * 68 + r0];
    *(float4*)(dotsg + ((size_t)blockIdx.x * 32 + b) * 64 + r0) = v0;
  }
}

// ---------------- combine K-halves + normalize + per-rg top-5 ----------------
__global__ void k_comb5(const float* __restrict__ dotsg, const float* __restrict__ normp,
                        float* __restrict__ norm2f, float* __restrict__ candv,
                        int* __restrict__ candi, int pass1, float eps) {
  __shared__ float sc[32 * 68];
  __shared__ float iv_lds[64];
  int rg = blockIdx.x;
  int tid = threadIdx.x;  // 256
  if (tid < 64) {
    int rw = rg * 64 + tid;
    int rc = rw < NROWS ? rw : NROWS - 1;
    float n2;
    if (pass1) {
      n2 = normp[rc] + normp[NROWS + rc];
      if (rw < NROWS) norm2f[rw] = n2;
    } else {
      n2 = norm2f[rc];
    }
    iv_lds[tid] = 1.0f / fmaxf(sqrtf(n2), eps);
  }
  __syncthreads();
  {
    int b = tid >> 3, r0 = (tid & 7) * 8;
    const float* p0 = dotsg + ((size_t)(rg * 2 + 0) * 32 + b) * 64 + r0;
    const float* p1 = dotsg + ((size_t)(rg * 2 + 1) * 32 + b) * 64 + r0;
    #pragma unroll
    for (int i = 0; i < 8; ++i)
      sc[b * 68 + r0 + i] = (p0[i] + p1[i]) * iv_lds[r0 + i];
  }
  __syncthreads();
  if (tid < 32) {
    float tv[5]; int ti[5];
    #pragma unroll
    for (int j = 0; j < 5; ++j) { tv[j] = -3.4e38f; ti[j] = 0x7fffffff; }
    int rbase = rg * 64;
    for (int rr = 0; rr < 64; ++rr) {
      int rw = rbase + rr;
      if (rw >= NROWS) break;
      float v = sc[tid * 68 + rr];
      if (v > tv[4] || (v == tv[4] && rw < ti[4])) {
        tv[4] = v; ti[4] = rw;
        #pragma unroll
        for (int j = 4; j > 0; --j) {
          bool sw = (tv[j] > tv[j-1]) || (tv[j] == tv[j-1] && ti[j] < ti[j-1]);
          if (sw) {
            float fv = tv[j]; tv[j] = tv[j-1]; tv[j-1] = fv;
            int ivx = ti[j]; ti[j] = ti[j-1]; ti[j-1] = ivx;
          }
        }
      }
    }
    #pragma unroll
    for (int j = 0; j < 5; ++j) {
      candv[((size_t)rg * 32 + tid) * 5 + j] = tv[j];
      candi[((size_t)rg * 32 + tid) * 5 + j] = ti[j];
    }
  }
}

// ---------------- merge per-rg candidates -> global top-K per batch ----------------
__global__ void k_merge(const float* __restrict__ candv, const int* __restrict__ candi,
                        int* __restrict__ out_idx, int K, int nblk) {
  int b = blockIdx.x;
  int tid = threadIdx.x; // 256
  float tv[5]; int ti[5];
  #pragma unroll
  for (int j = 0; j < 5; ++j) { tv[j] = -3.4e38f; ti[j] = 0x7fffffff; }
  for (int blk = tid; blk < nblk; blk += 256) {
    #pragma unroll
    for (int j = 0; j < 5; ++j) {
      float v = candv[((size_t)blk * 32 + b) * 5 + j];
      int idx = candi[((size_t)blk * 32 + b) * 5 + j];
      if (v > tv[4] || (v == tv[4] && idx < ti[4])) {
        tv[4] = v; ti[4] = idx;
        #pragma unroll
        for (int jj = 4; jj > 0; --jj) {
          bool sw = (tv[jj] > tv[jj-1]) || (tv[jj] == tv[jj-1] && ti[jj] < ti[jj-1]);
          if (sw) {
            float fv = tv[jj]; tv[jj] = tv[jj-1]; tv[jj-1] = fv;
            int ivx = ti[jj]; ti[jj] = ti[jj-1]; ti[jj-1] = ivx;
          }
        }
      }
    }
  }
  __shared__ float lv[256 * 5];
  __shared__ int   li[256 * 5];
  #pragma unroll
  for (int j = 0; j < 5; ++j) { lv[tid * 5 + j] = tv[j]; li[tid * 5 + j] = ti[j]; }
  __syncthreads();
  for (int off = 128; off >= 1; off >>= 1) {
    if (tid < off) {
      float av[5], bv[5]; int ai[5], bi[5];
      #pragma unroll
      for (int j = 0; j < 5; ++j) {
        av[j] = lv[tid * 5 + j]; ai[j] = li[tid * 5 + j];
        bv[j] = lv[(tid + off) * 5 + j]; bi[j] = li[(tid + off) * 5 + j];
      }
      int pa = 0, pb = 0;
      float mv[5]; int mi[5];
      #pragma unroll
      for (int j = 0; j < 5; ++j) {
        bool ta = (av[pa] > bv[pb]) || (av[pa] == bv[pb] && ai[pa] < bi[pb]);
        if (ta) { mv[j] = av[pa]; mi[j] = ai[pa]; ++pa; }
        else    { mv[j] = bv[pb]; mi[j] = bi[pb]; ++pb; }
      }
      #pragma unroll
      for (int j = 0; j < 5; ++j) { lv[tid * 5 + j] = mv[j]; li[tid * 5 + j] = mi[j]; }
    }
    __syncthreads();
  }
  if (tid == 0) {
    for (int j = 0; j < K; ++j) out_idx[b * K + j] = li[j];
  }
}

// ---------------- gathers ----------------
__global__ void k_gather_sel(const float* __restrict__ table, const int* __restrict__ best,
                             float* __restrict__ sel) {
  int b = blockIdx.x, e = threadIdx.x; // 1024
  int idx = best[b];
  sel[b * DMODEL + e] = table[(size_t)idx * DMODEL + e];
}

__global__ void k_gather_targets(const float* __restrict__ table, const int* __restrict__ idx5,
                                 float* __restrict__ tg) {
  int bt = blockIdx.x, e = threadIdx.x; // 1024
  int idx = idx5[bt];
  tg[(size_t)bt * DMODEL + e] = table[(size_t)idx * DMODEL + e];
}

// ---------------- attention over merged kv buffer [b*SEQ][2048]: K cols 0..1023, V cols 1024..2047 ----
__global__ __launch_bounds__(256) void k_attention(const float* __restrict__ q,
    const unsigned short* __restrict__ kv, float* __restrict__ obuf) {
  int bt = blockIdx.x;
  int b = bt / NTOPK;
  int tid = threadIdx.x; // 256
  __shared__ float q_l[DMODEL];
  __shared__ float sc[4][SEQ];
  #pragma unroll
  for (int j = 0; j < 4; ++j) q_l[tid + 256 * j] = q[(size_t)bt * DMODEL + tid + 256 * j];
  __syncthreads();
  { // scores: thread = key position s
    int s = tid;
    const unsigned short* krow = kv + ((size_t)(b * SEQ + s)) * 2048;
    #pragma unroll
    for (int h = 0; h < 4; ++h) {
      float d = 0.f;
      for (int dd = 0; dd < 256; dd += 8) {
        uint4 pk = *(const uint4*)(krow + h * 256 + dd);
        const unsigned short* ph = (const unsigned short*)&pk;
        #pragma unroll
        for (int j2 = 0; j2 < 8; ++j2) d += bf2f(ph[j2]) * q_l[h * 256 + dd + j2];
      }
      sc[h][s] = d * 0.0625f; // 1/sqrt(256)
    }
  }
  __syncthreads();
  { // softmax: wave w handles head h=w
    int h = tid >> 6, lane = tid & 63;
    float vals[4];
    float mx = -3.4e38f;
    #pragma unroll
    for (int j = 0; j < 4; ++j) { vals[j] = sc[h][lane + 64 * j]; mx = fmaxf(mx, vals[j]); }
    #pragma unroll
    for (int o = 1; o < 64; o <<= 1) mx = fmaxf(mx, __shfl_xor(mx, o));
    float sum = 0.f;
    #pragma unroll
    for (int j = 0; j < 4; ++j) { vals[j] = expf(vals[j] - mx); sum += vals[j]; }
    #pragma unroll
    for (int o = 1; o < 64; o <<= 1) sum += __shfl_xor(sum, o);
    float rz = 1.0f / sum;
    #pragma unroll
    for (int j = 0; j < 4; ++j) sc[h][lane + 64 * j] = vals[j] * rz;
  }
  __syncthreads();
  { // PV: thread owns 4 contiguous output dims
    int h = tid >> 6;
    int e0 = tid * 4;
    float a0 = 0.f, a1 = 0.f, a2 = 0.f, a3 = 0.f;
    const unsigned short* vbase = kv + (size_t)(b * SEQ) * 2048 + 1024 + e0;
    for (int s = 0; s < SEQ; ++s) {
      float w = sc[h][s];
      ushort4 v4 = *(const ushort4*)(vbase + (size_t)s * 2048);
      a0 += w * bf2f(v4.x); a1 += w * bf2f(v4.y); a2 += w * bf2f(v4.z); a3 += w * bf2f(v4.w);
    }
    float* op = obuf + (size_t)bt * DMODEL + e0;
    op[0] = a0; op[1] = a1; op[2] = a2; op[3] = a3;
  }
}

// ---------------- sum over the 5 queries ----------------
__global__ void k_osum(const float* __restrict__ obuf, float* __restrict__ osum) {
  int g = blockIdx.x * blockDim.x + threadIdx.x; // 32768
  if (g >= BATCH * DMODEL) return;
  int b = g >> 10, e = g & 1023;
  float s = 0.f;
  #pragma unroll
  for (int t = 0; t < NTOPK; ++t) s += obuf[(size_t)(b * NTOPK + t) * DMODEL + e];
  osum[g] = s;
}

extern "C" void kernel_launch(void* const* d_in, const int* in_sizes, int n_in,
                              void* d_out, int out_size, void* d_ws, size_t ws_size,
                              hipStream_t stream) {
  const float* hidden = (const float*)d_in[0];
  const float* table  = (const float*)d_in[1];
  const float* fc1_w  = (const float*)d_in[2];
  const float* fc1_b  = (const float*)d_in[3];
  const float* q_w    = (const float*)d_in[4];
  const float* q_b    = (const float*)d_in[5];
  const float* k_w    = (const float*)d_in[6];
  const float* k_b    = (const float*)d_in[7];
  const float* v_w    = (const float*)d_in[8];
  const float* v_b    = (const float*)d_in[9];
  const float* out_w  = (const float*)d_in[10];
  const float* out_b  = (const float*)d_in[11];
  float* out = (float*)d_out;

  char* ws = (char*)d_ws;
  size_t off = 0;
  auto alloc = [&](size_t bytes) -> void* {
    void* p = ws + off;
    off += (bytes + 255) & ~(size_t)255;
    return p;
  };
  unsigned short* hid_bf  = (unsigned short*)alloc((size_t)BATCH * SEQ * DIN * 2);
  unsigned short* fc1w_bf = (unsigned short*)alloc((size_t)DMODEL * DIN * 2);
  unsigned short* kvw_bf  = (unsigned short*)alloc((size_t)2 * DMODEL * DMODEL * 2);
  unsigned short* x_bf    = (unsigned short*)alloc((size_t)BATCH * SEQ * DMODEL * 2);
  unsigned short* kv_bf   = (unsigned short*)alloc((size_t)BATCH * SEQ * 2 * DMODEL * 2);
  unsigned short* qhi     = (unsigned short*)alloc((size_t)BATCH * DMODEL * 2);
  unsigned short* qlo     = (unsigned short*)alloc((size_t)BATCH * DMODEL * 2);
  float* hpart   = (float*)alloc((size_t)8 * BATCH * DIN * 4);
  float* hm      = (float*)alloc((size_t)BATCH * DIN * 4);
  float* m       = (float*)alloc((size_t)BATCH * DMODEL * 4);
  float* sel     = (float*)alloc((size_t)BATCH * DMODEL * 4);
  float* normp   = (float*)alloc((size_t)2 * NROWS * 4);
  float* norm2f  = (float*)alloc((size_t)NROWS * 4);
  float* dotsg   = (float*)alloc((size_t)DOTS_RG * 2 * 32 * 64 * 4);
  float* candv   = (float*)alloc((size_t)DOTS_RG * 32 * 5 * 4);
  int*   candi   = (int*)alloc((size_t)DOTS_RG * 32 * 5 * 4);
  int*   best    = (int*)alloc(BATCH * 4);
  int*   idx5    = (int*)alloc(BATCH * NTOPK * 4);
  float* targets = (float*)alloc((size_t)BATCH * NTOPK * DMODEL * 4);
  float* qbuf    = (float*)alloc((size_t)BATCH * NTOPK * DMODEL * 4);
  float* obuf    = (float*)alloc((size_t)BATCH * NTOPK * DMODEL * 4);
  float* osum    = (float*)alloc((size_t)BATCH * DMODEL * 4);
  (void)ws_size; (void)in_sizes; (void)n_in; (void)out_size;

  // fused hidden convert + mean partials; weight converts (k_w|v_w -> adjacent halves of kvw_bf)
  k_hidden_prep<<<256, 768, 0, stream>>>(hidden, hid_bf, hpart);
  k_f32_to_bf16_3<<<1024, 256, 0, stream>>>(fc1_w, fc1w_bf, DMODEL * DIN,
                                            k_w, kvw_bf, DMODEL * DMODEL,
                                            v_w, kvw_bf + (size_t)DMODEL * DMODEL, DMODEL * DMODEL);
  k_mean_reduce<<<32, 768, 0, stream>>>(hpart, hm);
  k_sgemm_wt<<<dim3(16, 1), 256, 0, stream>>>(hm, fc1_w, fc1_b, m, 32, DMODEL, DIN, 1.0f);

  // fc1: x (bf16)
  k_bf16_gemm<<<dim3(8, 64), 256, 0, stream>>>(hid_bf, fc1w_bf, fc1_b, nullptr, DMODEL,
                                               x_bf, BATCH * SEQ, DMODEL, DIN);

  // retrieval pass 1: cos argmax (8-wave K-split split-bf16 MFMA dots)
  k_split_q<<<32, 256, 0, stream>>>(m, qhi, qlo);
  k_dots<<<DOTS_RG * 2, 512, 0, stream>>>(table, qhi, qlo, normp, dotsg, 1);
  k_comb5<<<DOTS_RG, 256, 0, stream>>>(dotsg, normp, norm2f, candv, candi, 1, 1e-6f);
  k_merge<<<32, 256, 0, stream>>>(candv, candi, best, 1, DOTS_RG);
  k_gather_sel<<<32, 1024, 0, stream>>>(table, best, sel);

  // retrieval pass 2: top-5 by dot(sel, t_i)/||t_i|| (ranking-equivalent to ref d2)
  k_split_q<<<32, 256, 0, stream>>>(sel, qhi, qlo);
  k_dots<<<DOTS_RG * 2, 512, 0, stream>>>(table, qhi, qlo, normp, dotsg, 0);
  k_comb5<<<DOTS_RG, 256, 0, stream>>>(dotsg, normp, norm2f, candv, candi, 0, 1e-12f);
  k_merge<<<32, 256, 0, stream>>>(candv, candi, idx5, NTOPK, DOTS_RG);
  k_gather_targets<<<160, 1024, 0, stream>>>(table, idx5, targets);

  // q projection (fp32, small M)
  k_sgemm_wt<<<dim3(16, 5), 256, 0, stream>>>(targets, q_w, q_b, qbuf, BATCH * NTOPK, DMODEL, DMODEL, 1.0f);

  // merged K|V projection: kv = x @ [k_w|v_w]^T + [k_b|v_b]  (one N=2048 GEMM)
  k_bf16_gemm<<<dim3(16, 64), 256, 0, stream>>>(x_bf, kvw_bf, k_b, v_b, DMODEL,
                                                kv_bf, BATCH * SEQ, 2 * DMODEL, DMODEL);

  // attention + sum over queries + output projection
  k_attention<<<160, 256, 0, stream>>>(qbuf, kv_bf, obuf);
  k_osum<<<128, 256, 0, stream>>>(obuf, osum);
  k_sgemm_wt<<<dim3(16, 1), 256, 0, stream>>>(osum, out_w, out_b, out, 32, DMODEL, DMODEL, 5.0f);
}